// Round 1
// baseline (446.637 us; speedup 1.0000x reference)
//
#include <hip/hip_runtime.h>

#define B_N 131072
#define D_N 64

using bfrag_t = __attribute__((ext_vector_type(8))) short;  // 8 bf16 (MFMA A/B frag)
using acc_t   = __attribute__((ext_vector_type(4))) float;  // 4 fp32 (MFMA C/D frag)
using i32x4_t = __attribute__((ext_vector_type(4))) int;

__device__ __forceinline__ unsigned short f2bf(float f) {
  unsigned int u = __float_as_uint(f);
  u += 0x7FFFu + ((u >> 16) & 1u);   // RNE
  return (unsigned short)(u >> 16);
}

// exact GELU: 0.5x(1+erf(x/sqrt2)); erf via Abramowitz-Stegun 7.1.26, |eps|<=1.5e-7
__device__ __forceinline__ float gelu_f(float x) {
  float ax = fabsf(x) * 0.70710678118654752f;
  float t  = __builtin_amdgcn_rcpf(fmaf(0.3275911f, ax, 1.0f));
  float p  = fmaf(1.061405429f, t, -1.453152027f);
  p = fmaf(p, t, 1.421413741f);
  p = fmaf(p, t, -0.284496736f);
  p = fmaf(p, t, 0.254829592f);
  p = p * t;
  float e  = __expf(-ax * ax);
  float er = fmaf(-p, e, 1.0f);
  er = (x < 0.0f) ? -er : er;
  return 0.5f * x * (1.0f + er);
}

// ---------------- K1: prepack weights to bf16, transposed [t][n][k] ----------------
// W1: (4,128,128) [t][k][n] -> W1p[t][n][k] bf16 ; W2: (4,128,64) -> W2p[t][d][k]
__global__ __launch_bounds__(256) void prepack_k(const float* __restrict__ W1,
                                                 const float* __restrict__ W2,
                                                 short* __restrict__ W1p,
                                                 short* __restrict__ W2p) {
  int tid = blockIdx.x * 256 + threadIdx.x;  // 12288 total
  if (tid < 8192) {
    int t = tid >> 11, n = (tid >> 4) & 127, k8 = tid & 15;
    const float* src = W1 + t * 16384 + n;          // stride 128 over k
    short* dst = W1p + (t * 128 + n) * 128 + k8 * 8;
    #pragma unroll
    for (int j = 0; j < 8; j++) dst[j] = (short)f2bf(src[(k8 * 8 + j) * 128]);
  } else if (tid < 12288) {
    int r = tid - 8192;
    int t = r >> 10, d = (r >> 4) & 63, k8 = r & 15;
    const float* src = W2 + t * 8192 + d;           // stride 64 over k
    short* dst = W2p + (t * 64 + d) * 128 + k8 * 8;
    #pragma unroll
    for (int j = 0; j < 8; j++) dst[j] = (short)f2bf(src[(k8 * 8 + j) * 64]);
  }
}

// ---------------- K2: fp32 router, argmax -> r1/r2 bytes ----------------
// block=128 (2 waves): wave0 = routing1 ([a,b,pos]), wave1 = routing2 ([b,a,pos]),
// 64 samples per block, lane = sample. Inputs staged in LDS (stride 137: 2-way, free).
__global__ __launch_bounds__(128) void router_k(
    const float* __restrict__ a, const float* __restrict__ b,
    const float* __restrict__ pos, const float* __restrict__ Wr1,
    const float* __restrict__ br1, const float* __restrict__ Wr2,
    const float* __restrict__ br2,
    unsigned char* __restrict__ r1, unsigned char* __restrict__ r2) {
  __shared__ float XS[64 * 137];   // [s][0:64)=a, [64:128)=b, [128:136)=pos
  int tid = threadIdx.x;
  int s0 = blockIdx.x * 64;
  {
    int sl = tid >> 1, h = tid & 1;              // 2 threads per sample row
    const float* asrc = a + (s0 + sl) * 64 + h * 32;
    const float* bsrc = b + (s0 + sl) * 64 + h * 32;
    float* dst = XS + sl * 137;
    #pragma unroll
    for (int u = 0; u < 8; u++) {
      acc_t v = *(const acc_t*)(asrc + u * 4);
      int o = h * 32 + u * 4;
      dst[o] = v[0]; dst[o + 1] = v[1]; dst[o + 2] = v[2]; dst[o + 3] = v[3];
    }
    #pragma unroll
    for (int u = 0; u < 8; u++) {
      acc_t v = *(const acc_t*)(bsrc + u * 4);
      int o = 64 + h * 32 + u * 4;
      dst[o] = v[0]; dst[o + 1] = v[1]; dst[o + 2] = v[2]; dst[o + 3] = v[3];
    }
    acc_t v = *(const acc_t*)(pos + (s0 + sl) * 8 + h * 4);
    int o = 128 + h * 4;
    dst[o] = v[0]; dst[o + 1] = v[1]; dst[o + 2] = v[2]; dst[o + 3] = v[3];
  }
  __syncthreads();

  int lane = tid & 63, flip = tid >> 6;
  const float* xrow = XS + lane * 137;
  int off1 = flip ? 64 : 0;        // first 64 router inputs
  int off2 = 64 - off1;            // next 64
  float acc[64];
  #pragma unroll
  for (int j = 0; j < 64; j++) acc[j] = br1[j];
  for (int i = 0; i < 64; i++) {
    float x = xrow[off1 + i];
    const float* w = Wr1 + i * 64;      // uniform -> scalar loads
    #pragma unroll
    for (int j = 0; j < 64; j++) acc[j] = fmaf(x, w[j], acc[j]);
  }
  for (int i = 0; i < 64; i++) {
    float x = xrow[off2 + i];
    const float* w = Wr1 + (64 + i) * 64;
    #pragma unroll
    for (int j = 0; j < 64; j++) acc[j] = fmaf(x, w[j], acc[j]);
  }
  #pragma unroll
  for (int i = 0; i < 8; i++) {
    float x = xrow[128 + i];
    const float* w = Wr1 + (128 + i) * 64;
    #pragma unroll
    for (int j = 0; j < 64; j++) acc[j] = fmaf(x, w[j], acc[j]);
  }
  float l0 = br2[0], l1 = br2[1], l2 = br2[2], l3 = br2[3];
  #pragma unroll
  for (int j = 0; j < 64; j++) {
    float h = gelu_f(acc[j]);
    l0 = fmaf(h, Wr2[j * 4 + 0], l0);
    l1 = fmaf(h, Wr2[j * 4 + 1], l1);
    l2 = fmaf(h, Wr2[j * 4 + 2], l2);
    l3 = fmaf(h, Wr2[j * 4 + 3], l3);
  }
  // argmax, first-max tie-break (TEMP>0 scaling is argmax-invariant)
  int idx = 0; float best = l0;
  if (l1 > best) { best = l1; idx = 1; }
  if (l2 > best) { best = l2; idx = 2; }
  if (l3 > best) { best = l3; idx = 3; }
  int s = s0 + lane;
  if (flip == 0) r1[s] = (unsigned char)idx;
  else           r2[s] = (unsigned char)idx;
}

// ---------------- K3: all-4 experts via bf16 MFMA (transposed GEMM), select ----------------
// block=256 (4 waves), 64 samples/block; wave w owns 16 samples (sgrp=w).
// Layer1: h^T = A(W1^T) x B(pair^T); layer2: out^T = A(W2^T) x B(h^T via ds_bpermute).
__global__ __launch_bounds__(256) void expert_k(
    const float* __restrict__ a, const float* __restrict__ b,
    const short* __restrict__ W1p, const short* __restrict__ W2p,
    const float* __restrict__ b1, const float* __restrict__ b2,
    const unsigned char* __restrict__ r1, const unsigned char* __restrict__ r2,
    float* __restrict__ out) {
  __shared__ short FB[16 * 64 * 8];  // 16 KB: frag f=(sgrp*4+kb), lane-linear 16B slots
  int tid = threadIdx.x;
  int s0 = blockIdx.x * 64;

  // stage pair^T B-fragments: slot(f,l): pair[s0+sgrp*16+(l&15)][kb*32+(l>>4)*8 .. +8]
  #pragma unroll
  for (int r = 0; r < 4; r++) {
    int slot = tid + r * 256;
    int f = slot >> 6, l = slot & 63;
    int sgrp = f >> 2, kb = f & 3;
    int qq = l >> 4, ss = l & 15;
    int s = s0 + sgrp * 16 + ss;
    int k = kb * 32 + qq * 8;
    const float* src = (k < 64) ? (a + s * 64 + k) : (b + s * 64 + (k - 64));
    acc_t v0 = *(const acc_t*)(src);
    acc_t v1 = *(const acc_t*)(src + 4);
    bfrag_t pk;
    pk[0] = (short)f2bf(v0[0]); pk[1] = (short)f2bf(v0[1]);
    pk[2] = (short)f2bf(v0[2]); pk[3] = (short)f2bf(v0[3]);
    pk[4] = (short)f2bf(v1[0]); pk[5] = (short)f2bf(v1[1]);
    pk[6] = (short)f2bf(v1[2]); pk[7] = (short)f2bf(v1[3]);
    *(bfrag_t*)(&FB[slot * 8]) = pk;
  }
  __syncthreads();

  int lane = tid & 63, wave = tid >> 6;
  int q = lane >> 4, sm = lane & 15;
  int s_out = s0 + wave * 16 + sm;
  int i1 = (int)r1[s_out];
  int i2 = (int)r2[s_out];

  bfrag_t bfrag[4];
  #pragma unroll
  for (int kb = 0; kb < 4; kb++)
    bfrag[kb] = *(const bfrag_t*)(&FB[((wave * 4 + kb) * 64 + lane) * 8]);

  acc_t zero = {0.f, 0.f, 0.f, 0.f};
  acc_t o1[4], o2[4];
  #pragma unroll
  for (int i = 0; i < 4; i++) { o1[i] = zero; o2[i] = zero; }

  int addr0 = (((q & 1) * 2) * 16 + sm) * 4;  // src lane qa*16+sm (bytes)
  int addr1 = addr0 + 64;                      // src lane (qa+1)*16+sm
  bool hi = (q >> 1) != 0;

  for (int t = 0; t < 4; t++) {
    // ---- layer 1: h^T (rows = hidden n, cols = sample) ----
    unsigned int hp[8][2];
    #pragma unroll
    for (int mt = 0; mt < 8; mt++) {
      acc_t c = zero;
      #pragma unroll
      for (int kb = 0; kb < 4; kb++) {
        const bfrag_t* ap =
            (const bfrag_t*)(W1p + ((t * 128 + mt * 16 + sm) * 128 + kb * 32 + q * 8));
        c = __builtin_amdgcn_mfma_f32_16x16x32_bf16(*ap, bfrag[kb], c, 0, 0, 0);
      }
      const float* b1p = b1 + t * 128 + mt * 16 + q * 4;  // rows n = mt*16+q*4+reg
      float g0 = gelu_f(c[0] + b1p[0]);
      float g1 = gelu_f(c[1] + b1p[1]);
      float g2 = gelu_f(c[2] + b1p[2]);
      float g3 = gelu_f(c[3] + b1p[3]);
      hp[mt][0] = (unsigned int)f2bf(g0) | ((unsigned int)f2bf(g1) << 16);
      hp[mt][1] = (unsigned int)f2bf(g2) | ((unsigned int)f2bf(g3) << 16);
    }
    // ---- redistribute h^T C-frags -> layer-2 B-frags (wave-local bpermute) ----
    bfrag_t b2f[4];
    #pragma unroll
    for (int kb2 = 0; kb2 < 4; kb2++) {
      int p00 = __builtin_amdgcn_ds_bpermute(addr0, (int)hp[2 * kb2][0]);
      int p01 = __builtin_amdgcn_ds_bpermute(addr0, (int)hp[2 * kb2][1]);
      int p10 = __builtin_amdgcn_ds_bpermute(addr1, (int)hp[2 * kb2][0]);
      int p11 = __builtin_amdgcn_ds_bpermute(addr1, (int)hp[2 * kb2][1]);
      int q00 = __builtin_amdgcn_ds_bpermute(addr0, (int)hp[2 * kb2 + 1][0]);
      int q01 = __builtin_amdgcn_ds_bpermute(addr0, (int)hp[2 * kb2 + 1][1]);
      int q10 = __builtin_amdgcn_ds_bpermute(addr1, (int)hp[2 * kb2 + 1][0]);
      int q11 = __builtin_amdgcn_ds_bpermute(addr1, (int)hp[2 * kb2 + 1][1]);
      i32x4_t w;
      w[0] = hi ? q00 : p00;
      w[1] = hi ? q01 : p01;
      w[2] = hi ? q10 : p10;
      w[3] = hi ? q11 : p11;
      b2f[kb2] = __builtin_bit_cast(bfrag_t, w);
    }
    // ---- layer 2 + per-sample select ----
    #pragma unroll
    for (int mt2 = 0; mt2 < 4; mt2++) {
      acc_t c = zero;
      #pragma unroll
      for (int kb2 = 0; kb2 < 4; kb2++) {
        const bfrag_t* ap =
            (const bfrag_t*)(W2p + ((t * 64 + mt2 * 16 + sm) * 128 + kb2 * 32 + q * 8));
        c = __builtin_amdgcn_mfma_f32_16x16x32_bf16(*ap, b2f[kb2], c, 0, 0, 0);
      }
      const float* b2p = b2 + t * 64 + mt2 * 16 + q * 4;
      c[0] += b2p[0]; c[1] += b2p[1]; c[2] += b2p[2]; c[3] += b2p[3];
      o1[mt2] = (i1 == t) ? c : o1[mt2];
      o2[mt2] = (i2 == t) ? c : o2[mt2];
    }
  }
  // store: rows d = mt2*16+q*4+reg for sample s_out -> dwordx4
  float* o1base = out + s_out * 64 + q * 4;
  float* o2base = out + (size_t)B_N * 64 + s_out * 64 + q * 4;
  #pragma unroll
  for (int mt2 = 0; mt2 < 4; mt2++) {
    *(acc_t*)(o1base + mt2 * 16) = o1[mt2];
    *(acc_t*)(o2base + mt2 * 16) = o2[mt2];
  }
}

extern "C" void kernel_launch(void* const* d_in, const int* in_sizes, int n_in,
                              void* d_out, int out_size, void* d_ws, size_t ws_size,
                              hipStream_t stream) {
  const float* a   = (const float*)d_in[0];
  const float* bv  = (const float*)d_in[1];
  const float* pos = (const float*)d_in[2];
  const float* Wr1 = (const float*)d_in[3];
  const float* br1 = (const float*)d_in[4];
  const float* Wr2 = (const float*)d_in[5];
  const float* br2 = (const float*)d_in[6];
  const float* W1  = (const float*)d_in[7];
  const float* b1  = (const float*)d_in[8];
  const float* W2  = (const float*)d_in[9];
  const float* b2  = (const float*)d_in[10];
  float* out = (float*)d_out;

  unsigned char* r1 = (unsigned char*)d_ws;
  unsigned char* r2 = r1 + B_N;
  short* W1p = (short*)((char*)d_ws + 2 * B_N);
  short* W2p = W1p + 4 * 128 * 128;

  prepack_k<<<48, 256, 0, stream>>>(W1, W2, W1p, W2p);
  router_k<<<B_N / 64, 128, 0, stream>>>(a, bv, pos, Wr1, br1, Wr2, br2, r1, r2);
  expert_k<<<B_N / 64, 256, 0, stream>>>(a, bv, W1p, W2p, b1, b2, r1, r2, out);
}

// Round 6
// 273.122 us; speedup vs baseline: 1.6353x; 1.6353x over previous
//
#include <hip/hip_runtime.h>

#define B_N 131072

using bfrag_t = __attribute__((ext_vector_type(8))) short;  // 8 bf16 (MFMA A/B frag)
using acc_t   = __attribute__((ext_vector_type(4))) float;  // 4 fp32 (MFMA C/D frag)
using v4f     = __attribute__((ext_vector_type(4))) float;
using i32x4_t = __attribute__((ext_vector_type(4))) int;

__device__ __forceinline__ unsigned short f2bf(float f) {
  unsigned int u = __float_as_uint(f);
  u += 0x7FFFu + ((u >> 16) & 1u);   // RNE
  return (unsigned short)(u >> 16);
}

__device__ __forceinline__ unsigned int pk2bf(float x, float y) {
  return (unsigned int)f2bf(x) | ((unsigned int)f2bf(y) << 16);
}

// async global->LDS, 16B per lane; lds base must be wave-uniform (lane-linear dest)
__device__ __forceinline__ void gload_lds16(const void* g, void* l) {
  __builtin_amdgcn_global_load_lds((const __attribute__((address_space(1))) void*)g,
                                   (__attribute__((address_space(3))) void*)l, 16, 0, 0);
}

// exact GELU: 0.5x(1+erf(x/sqrt2)); erf via Abramowitz-Stegun 7.1.26, |eps|<=1.5e-7
__device__ __forceinline__ float gelu_f(float x) {
  float ax = fabsf(x) * 0.70710678118654752f;
  float t  = __builtin_amdgcn_rcpf(fmaf(0.3275911f, ax, 1.0f));
  float p  = fmaf(1.061405429f, t, -1.453152027f);
  p = fmaf(p, t, 1.421413741f);
  p = fmaf(p, t, -0.284496736f);
  p = fmaf(p, t, 0.254829592f);
  p = p * t;
  float e  = __expf(-ax * ax);
  float er = fmaf(-p, e, 1.0f);
  er = (x < 0.0f) ? -er : er;
  return 0.5f * x * (1.0f + er);
}

// ---------------- K1: prepack ----------------
// RW blob (fp32, rows of 64): 0-135 Wr1 (as-is), 136 br1, 137-140 Wr2 flat(256),
//   141 br2(+pad). NO algebraic rewrite: router must replicate the reference's
//   fp32 fma sequence bit-exactly (argmax-flip safety — see round 4 post-mortem).
// W1s/W2s: bf16, [t][row n|d][16 chunks of k8], chunk c stored at (c ^ (row&15))
// so that flat global_load_lds -> LDS gives bank-uniform swizzled A-frags.
__global__ __launch_bounds__(256) void prepack2_k(
    const float* __restrict__ Wr1, const float* __restrict__ br1,
    const float* __restrict__ Wr2, const float* __restrict__ br2,
    const float* __restrict__ W1, const float* __restrict__ W2,
    float* __restrict__ RW, short* __restrict__ W1s, short* __restrict__ W2s) {
  int gt = blockIdx.x * 256 + threadIdx.x;   // grid 64 -> 16384 threads
  for (int idx = gt; idx < 142 * 64; idx += 16384) {
    int row = idx >> 6, j = idx & 63; float val;
    if (row < 136)      val = Wr1[row * 64 + j];
    else if (row == 136) val = br1[j];
    else if (row < 141) val = Wr2[(row - 137) * 64 + j];
    else                val = (j < 4) ? br2[j] : 0.0f;
    RW[idx] = val;
  }
  for (int ch = gt; ch < 8192; ch += 16384) {  // W1: (4,128,128) [t][k][n]
    int t = ch >> 11, r = (ch >> 4) & 127, c = ch & 15;
    const float* src = W1 + t * 16384 + r;     // stride 128 over k
    short* dst = W1s + (t * 128 + r) * 128 + ((c ^ (r & 15)) * 8);
    #pragma unroll
    for (int m = 0; m < 8; m++) dst[m] = (short)f2bf(src[(c * 8 + m) * 128]);
  }
  for (int ch = gt; ch < 4096; ch += 16384) {  // W2: (4,128,64) [t][k][d]
    int t = ch >> 10, d = (ch >> 4) & 63, c = ch & 15;
    const float* src = W2 + t * 8192 + d;      // stride 64 over k
    short* dst = W2s + (t * 64 + d) * 128 + ((c ^ (d & 15)) * 8);
    #pragma unroll
    for (int m = 0; m < 8; m++) dst[m] = (short)f2bf(src[(c * 8 + m) * 64]);
  }
}

// ---------------- K2: router (fp32, BOTH routings direct, round-1 bit order) ------
// lane = sample. Per output j, acc1: br1 -> +a_i*W[i][j] (i asc) -> +b_i*W[64+i][j]
// -> +p_i*W[128+i][j]; acc2 same with a/b swapped. Identical fma sequence to the
// round-1 passing kernel => identical argmax decisions.
__global__ __launch_bounds__(256) void router4_k(
    const float* __restrict__ a, const float* __restrict__ b,
    const float* __restrict__ pos, const float* __restrict__ RW,
    unsigned char* __restrict__ r1, unsigned char* __restrict__ r2) {
  __shared__ float WB[142 * 64];
  int tid = threadIdx.x, wave = tid >> 6, lane = tid & 63;
  for (int it = 0; it < 9; it++) {           // 2272 16B chunks
    int cb = it * 256 + wave * 64;
    if (cb < 2272) {
      int chunk = cb + lane;
      if (chunk < 2272) gload_lds16(RW + chunk * 4, (char*)WB + cb * 16);
    }
  }
  __syncthreads();
  int s = blockIdx.x * 256 + tid;
  v4f acc1[16], acc2[16];
  #pragma unroll
  for (int c = 0; c < 16; c++) {
    v4f binit = *(const v4f*)(WB + 136 * 64 + c * 4);
    acc1[c] = binit; acc2[c] = binit;
  }
  const acc_t* arow = (const acc_t*)(a + (size_t)s * 64);
  const acc_t* brow = (const acc_t*)(b + (size_t)s * 64);
  // phase 1: rows 0..63 (Wtop): acc1 += a_i*W[i], acc2 += b_i*W[i]
  #pragma unroll 2
  for (int c4 = 0; c4 < 16; c4++) {
    acc_t av = arow[c4], bv = brow[c4];
    #pragma unroll
    for (int e = 0; e < 4; e++) {
      float x1 = av[e], x2 = bv[e];
      v4f x1v = {x1, x1, x1, x1}, x2v = {x2, x2, x2, x2};
      const v4f* w = (const v4f*)(WB + (c4 * 4 + e) * 64);
      #pragma unroll
      for (int c = 0; c < 16; c++) {
        acc1[c] = __builtin_elementwise_fma(x1v, w[c], acc1[c]);
        acc2[c] = __builtin_elementwise_fma(x2v, w[c], acc2[c]);
      }
    }
  }
  // phase 2: rows 64..127 (Wbot): acc1 += b_i*W[64+i], acc2 += a_i*W[64+i]
  #pragma unroll 2
  for (int c4 = 0; c4 < 16; c4++) {
    acc_t av = arow[c4], bv = brow[c4];
    #pragma unroll
    for (int e = 0; e < 4; e++) {
      float x1 = bv[e], x2 = av[e];
      v4f x1v = {x1, x1, x1, x1}, x2v = {x2, x2, x2, x2};
      const v4f* w = (const v4f*)(WB + (64 + c4 * 4 + e) * 64);
      #pragma unroll
      for (int c = 0; c < 16; c++) {
        acc1[c] = __builtin_elementwise_fma(x1v, w[c], acc1[c]);
        acc2[c] = __builtin_elementwise_fma(x2v, w[c], acc2[c]);
      }
    }
  }
  // pos: rows 128..135, both routings
  {
    const acc_t* prow = (const acc_t*)(pos + (size_t)s * 8);
    #pragma unroll
    for (int h = 0; h < 2; h++) {
      acc_t pv = prow[h];
      #pragma unroll
      for (int e = 0; e < 4; e++) {
        float p = pv[e];
        v4f p4 = {p, p, p, p};
        const v4f* wp = (const v4f*)(WB + (128 + h * 4 + e) * 64);
        #pragma unroll
        for (int c = 0; c < 16; c++) {
          acc1[c] = __builtin_elementwise_fma(p4, wp[c], acc1[c]);
          acc2[c] = __builtin_elementwise_fma(p4, wp[c], acc2[c]);
        }
      }
    }
  }
  v4f l1 = *(const v4f*)(WB + 141 * 64);
  v4f l2 = l1;
  #pragma unroll
  for (int c = 0; c < 16; c++) {
    #pragma unroll
    for (int m = 0; m < 4; m++) {
      float h1 = gelu_f(acc1[c][m]), h2 = gelu_f(acc2[c][m]);
      v4f w2 = *(const v4f*)(WB + 137 * 64 + (c * 4 + m) * 4);
      v4f h1v = {h1, h1, h1, h1}, h2v = {h2, h2, h2, h2};
      l1 = __builtin_elementwise_fma(h1v, w2, l1);
      l2 = __builtin_elementwise_fma(h2v, w2, l2);
    }
  }
  int idx1 = 0; float b1v = l1[0];
  if (l1[1] > b1v) { b1v = l1[1]; idx1 = 1; }
  if (l1[2] > b1v) { b1v = l1[2]; idx1 = 2; }
  if (l1[3] > b1v) { b1v = l1[3]; idx1 = 3; }
  int idx2 = 0; float b2v = l2[0];
  if (l2[1] > b2v) { b2v = l2[1]; idx2 = 1; }
  if (l2[2] > b2v) { b2v = l2[2]; idx2 = 2; }
  if (l2[3] > b2v) { b2v = l2[3]; idx2 = 3; }
  r1[s] = (unsigned char)idx1;
  r2[s] = (unsigned char)idx2;
}

// ---------------- K3: experts, LDS-phased weights + MFMA -------------------------
// block=256 (4 waves), 128 samples (2 groups of 64); wave owns 16 samples/group.
__global__ __launch_bounds__(256) void expert2_k(
    const float* __restrict__ a, const float* __restrict__ b,
    const short* __restrict__ W1s, const short* __restrict__ W2s,
    const float* __restrict__ b1, const float* __restrict__ b2,
    const unsigned char* __restrict__ r1, const unsigned char* __restrict__ r2,
    float* __restrict__ out) {
  __shared__ short LB[24576];  // 48KB; overlaid: pair-frag staging (32KB) then weights
  int tid = threadIdx.x;
  int wave = tid >> 6, lane = tid & 63;
  int q = lane >> 4, sm = lane & 15;
  int s0 = blockIdx.x * 128;

  // stage pair^T B-fragments for both groups (lane-linear 16B slots)
  #pragma unroll
  for (int r = 0; r < 8; r++) {
    int slot = r * 256 + tid;                 // 2048 slots
    int g = slot >> 10, sg = slot & 1023;
    int f = sg >> 6, l = sg & 63;
    int sgrp = f >> 2, kb = f & 3;
    int s = s0 + g * 64 + sgrp * 16 + (l & 15);
    int k = kb * 32 + (l >> 4) * 8;
    const float* src = (k < 64) ? (a + s * 64 + k) : (b + s * 64 + (k - 64));
    acc_t v0 = *(const acc_t*)(src);
    acc_t v1 = *(const acc_t*)(src + 4);
    i32x4_t pk;
    pk[0] = (int)pk2bf(v0[0], v0[1]);
    pk[1] = (int)pk2bf(v0[2], v0[3]);
    pk[2] = (int)pk2bf(v1[0], v1[1]);
    pk[3] = (int)pk2bf(v1[2], v1[3]);
    *(i32x4_t*)(&LB[slot * 8]) = pk;
  }
  __syncthreads();
  bfrag_t bfrag[2][4];
  #pragma unroll
  for (int g = 0; g < 2; g++)
    #pragma unroll
    for (int kb = 0; kb < 4; kb++)
      bfrag[g][kb] = *(const bfrag_t*)(&LB[((g * 16 + wave * 4 + kb) * 64 + lane) * 8]);

  int sA = s0 + wave * 16 + sm, sB = sA + 64;
  int i1A = (int)r1[sA], i2A = (int)r2[sA];
  int i1B = (int)r1[sB], i2B = (int)r2[sB];
  __syncthreads();   // all frag reads done before weights overwrite LB

  acc_t zero = {0.f, 0.f, 0.f, 0.f};
  acc_t o1[2][4], o2[2][4];
  #pragma unroll
  for (int g = 0; g < 2; g++)
    #pragma unroll
    for (int i = 0; i < 4; i++) { o1[g][i] = zero; o2[g][i] = zero; }

  int vb[4];
  #pragma unroll
  for (int kb = 0; kb < 4; kb++) vb[kb] = sm * 256 + (((kb * 4 + q) ^ sm) * 16);
  int addr0 = (((q & 1) * 2) * 16 + sm) * 4;
  int addr1 = addr0 + 64;
  bool hi = (q >> 1) != 0;

  for (int t = 0; t < 4; t++) {
    // stage expert t: W1s 32KB (2048 chunks) + W2s 16KB (1024 chunks) = 3072 chunks
    #pragma unroll
    for (int it = 0; it < 12; it++) {
      int cb = it * 256 + wave * 64;          // wave-uniform base
      int chunk = cb + lane;
      const short* gsrc = (chunk < 2048) ? (W1s + t * 16384 + chunk * 8)
                                         : (W2s + t * 8192 + (chunk - 2048) * 8);
      gload_lds16(gsrc, (char*)LB + cb * 16);
    }
    __syncthreads();
    #pragma unroll
    for (int g = 0; g < 2; g++) {
      // layer 1: h^T
      unsigned int hp[8][2];
      #pragma unroll
      for (int mt = 0; mt < 8; mt++) {
        acc_t c = zero;
        #pragma unroll
        for (int kb = 0; kb < 4; kb++) {
          bfrag_t A = *(const bfrag_t*)((const char*)LB + mt * 4096 + vb[kb]);
          c = __builtin_amdgcn_mfma_f32_16x16x32_bf16(A, bfrag[g][kb], c, 0, 0, 0);
        }
        acc_t bv = *(const acc_t*)(b1 + t * 128 + mt * 16 + q * 4);
        float g0 = gelu_f(c[0] + bv[0]);
        float g1 = gelu_f(c[1] + bv[1]);
        float g2 = gelu_f(c[2] + bv[2]);
        float g3 = gelu_f(c[3] + bv[3]);
        hp[mt][0] = pk2bf(g0, g1);
        hp[mt][1] = pk2bf(g2, g3);
      }
      // redistribute h^T C-frags -> layer-2 B-frags (wave-local bpermute)
      bfrag_t b2f[4];
      #pragma unroll
      for (int kb2 = 0; kb2 < 4; kb2++) {
        int p00 = __builtin_amdgcn_ds_bpermute(addr0, (int)hp[2 * kb2][0]);
        int p01 = __builtin_amdgcn_ds_bpermute(addr0, (int)hp[2 * kb2][1]);
        int p10 = __builtin_amdgcn_ds_bpermute(addr1, (int)hp[2 * kb2][0]);
        int p11 = __builtin_amdgcn_ds_bpermute(addr1, (int)hp[2 * kb2][1]);
        int q00 = __builtin_amdgcn_ds_bpermute(addr0, (int)hp[2 * kb2 + 1][0]);
        int q01 = __builtin_amdgcn_ds_bpermute(addr0, (int)hp[2 * kb2 + 1][1]);
        int q10 = __builtin_amdgcn_ds_bpermute(addr1, (int)hp[2 * kb2 + 1][0]);
        int q11 = __builtin_amdgcn_ds_bpermute(addr1, (int)hp[2 * kb2 + 1][1]);
        i32x4_t w;
        w[0] = hi ? q00 : p00;
        w[1] = hi ? q01 : p01;
        w[2] = hi ? q10 : p10;
        w[3] = hi ? q11 : p11;
        b2f[kb2] = __builtin_bit_cast(bfrag_t, w);
      }
      // layer 2 + per-sample select
      int i1g = g ? i1B : i1A;
      int i2g = g ? i2B : i2A;
      #pragma unroll
      for (int mt2 = 0; mt2 < 4; mt2++) {
        acc_t c = zero;
        #pragma unroll
        for (int kb2 = 0; kb2 < 4; kb2++) {
          bfrag_t A = *(const bfrag_t*)((const char*)LB + 32768 + mt2 * 4096 + vb[kb2]);
          c = __builtin_amdgcn_mfma_f32_16x16x32_bf16(A, b2f[kb2], c, 0, 0, 0);
        }
        acc_t bv = *(const acc_t*)(b2 + t * 64 + mt2 * 16 + q * 4);
        c[0] += bv[0]; c[1] += bv[1]; c[2] += bv[2]; c[3] += bv[3];
        o1[g][mt2] = (i1g == t) ? c : o1[g][mt2];
        o2[g][mt2] = (i2g == t) ? c : o2[g][mt2];
      }
    }
    __syncthreads();   // compute done before next phase overwrites LB
  }
  #pragma unroll
  for (int g = 0; g < 2; g++) {
    int so = g ? sB : sA;
    float* p1 = out + so * 64 + q * 4;
    float* p2 = out + (size_t)B_N * 64 + so * 64 + q * 4;
    #pragma unroll
    for (int mt2 = 0; mt2 < 4; mt2++) {
      *(acc_t*)(p1 + mt2 * 16) = o1[g][mt2];
      *(acc_t*)(p2 + mt2 * 16) = o2[g][mt2];
    }
  }
}

extern "C" void kernel_launch(void* const* d_in, const int* in_sizes, int n_in,
                              void* d_out, int out_size, void* d_ws, size_t ws_size,
                              hipStream_t stream) {
  const float* a   = (const float*)d_in[0];
  const float* bv  = (const float*)d_in[1];
  const float* pos = (const float*)d_in[2];
  const float* Wr1 = (const float*)d_in[3];
  const float* br1 = (const float*)d_in[4];
  const float* Wr2 = (const float*)d_in[5];
  const float* br2 = (const float*)d_in[6];
  const float* W1  = (const float*)d_in[7];
  const float* b1  = (const float*)d_in[8];
  const float* W2  = (const float*)d_in[9];
  const float* b2  = (const float*)d_in[10];
  float* out = (float*)d_out;

  // ws layout (BYTES): r1 [0,131072) r2 [131072,262144) RW [262144,298496)
  // W1s [298496, 298496+131072=429568)  <-- 4*128*128 SHORTS = 131072 BYTES
  // W2s [429568, 429568+65536=495104)   (round-5 bug: W2s at +65536 B overlapped
  //                                      W1s experts t=2,3 -> prepack race)
  unsigned char* r1 = (unsigned char*)d_ws;
  unsigned char* r2 = r1 + B_N;
  float* RW  = (float*)((char*)d_ws + 262144);
  short* W1s = (short*)((char*)d_ws + 298496);
  short* W2s = (short*)((char*)d_ws + 429568);

  prepack2_k<<<64, 256, 0, stream>>>(Wr1, br1, Wr2, br2, W1, W2, RW, W1s, W2s);
  router4_k<<<B_N / 256, 256, 0, stream>>>(a, bv, pos, RW, r1, r2);
  expert2_k<<<B_N / 128, 256, 0, stream>>>(a, bv, W1s, W2s, b1, b2, r1, r2, out);
}